// Round 17
// baseline (199.454 us; speedup 1.0000x reference)
//
#include <hip/hip_runtime.h>
#include <hip/hip_fp16.h>

// Problem constants (match reference)
constexpr int   N_NODES = 80000;
constexpr int   N_EDGE  = 2560000;
constexpr int   IN_DIM  = 128;
constexpr int   H1      = 32;
constexpr int   H2      = 64;
constexpr int   NPB     = 10000;   // nodes per batch
constexpr int   NB      = 8;       // batches
constexpr int   G2_BLOCKS = N_NODES / 4;        // 20000 (4 nodes per block)
constexpr int   BLK_PER_BATCH = G2_BLOCKS / NB; // 2500

// binned-fill parameters (static bucket capacity, 256 nodes per bucket)
constexpr int   BKT_SHIFT = 8;                       // 256 nodes per bucket
constexpr int   BKT_N     = 1 << BKT_SHIFT;          // 256
constexpr int   NBKT      = (N_NODES + BKT_N - 1) >> BKT_SHIFT;  // 313
constexpr int   BBSTRIDE  = 16;                      // pad bucket counters to 64 B
constexpr unsigned SBKT_CAP = 9216;                  // mean 8192 + ~11 sigma
constexpr int   BF_EPB    = 8192;                    // edges per binfill block
constexpr int   BF_BLOCKS = (N_EDGE + BF_EPB - 1) / BF_EPB;  // 313
constexpr int   BF_THREADS = 512;

// gemm1 tile parameters
constexpr int   G1_ROWS   = 64;                      // rows per block tile
constexpr int   G1_BLOCKS = N_NODES / G1_ROWS;       // 1250

// ---------------- seed bucket bumps with static bases ----------------
__global__ void k_initb(unsigned* __restrict__ bbump) {
    int i = blockIdx.x * blockDim.x + threadIdx.x;
    if (i < NBKT) bbump[i * BBSTRIDE] = (unsigned)i * SBKT_CAP;
}

// ------- binned fill: stage[pos] = (src<<8)|d_local, dense per bucket ------
__global__ __launch_bounds__(BF_THREADS) void k_binfill(
        const int* __restrict__ ei, unsigned* __restrict__ bbump,
        unsigned* __restrict__ stage) {
    __shared__ unsigned hist[NBKT];
    __shared__ unsigned base[NBKT];
    int t = threadIdx.x;
    int e0 = blockIdx.x * BF_EPB;
    int e1 = min(e0 + BF_EPB, N_EDGE);
    for (int i = t; i < NBKT; i += BF_THREADS) hist[i] = 0u;
    __syncthreads();
    for (int e = e0 + t; e < e1; e += BF_THREADS) {
        int d = ei[N_EDGE + e];
        atomicAdd(&hist[d >> BKT_SHIFT], 1u);
    }
    __syncthreads();
    for (int i = t; i < NBKT; i += BF_THREADS) {
        unsigned h = hist[i];
        base[i] = h ? atomicAdd(&bbump[i * BBSTRIDE], h) : 0u;
        hist[i] = 0u;
    }
    __syncthreads();
    for (int e = e0 + t; e < e1; e += BF_THREADS) {
        int s = ei[e];
        int d = ei[N_EDGE + e];
        int bkt = d >> BKT_SHIFT;
        unsigned lp = atomicAdd(&hist[bkt], 1u);
        unsigned pos = base[bkt] + lp;
        if (pos < (unsigned)(bkt + 1) * SBKT_CAP)   // capacity guard (never hit)
            stage[pos] = ((unsigned)s << BKT_SHIFT) | (unsigned)(d & (BKT_N - 1));
    }
}

// ------- place: per-bucket degrees (LDS) -> row_ptr, rend, dinv, csr -------
__global__ __launch_bounds__(256) void k_place(
        const unsigned* __restrict__ bbump, const unsigned* __restrict__ stage,
        int* __restrict__ csr, unsigned* __restrict__ row_ptr,
        unsigned* __restrict__ rend, float* __restrict__ dinv) {
    __shared__ unsigned cnt[BKT_N];
    __shared__ unsigned sc[BKT_N];
    __shared__ unsigned nb[BKT_N];
    int b = blockIdx.x;
    int t = threadIdx.x;              // 256 threads == BKT_N
    unsigned beg = (unsigned)b * SBKT_CAP;
    unsigned end = min(bbump[b * BBSTRIDE], (unsigned)(b + 1) * SBKT_CAP);
    cnt[t] = 0u;
    __syncthreads();
    for (unsigned j = beg + (unsigned)t; j < end; j += 256)
        atomicAdd(&cnt[stage[j] & (BKT_N - 1u)], 1u);
    __syncthreads();
    sc[t] = cnt[t];
    for (int ofs = 1; ofs < BKT_N; ofs <<= 1) {
        __syncthreads();
        unsigned u = (t >= ofs) ? sc[t - ofs] : 0u;
        __syncthreads();
        sc[t] += u;
    }
    __syncthreads();
    {
        unsigned nodebase = beg + sc[t] - cnt[t];
        int node = (b << BKT_SHIFT) + t;
        if (node < N_NODES) {
            row_ptr[node] = nodebase;
            rend[node]    = nodebase + cnt[t];
            dinv[node] = rsqrtf((float)(cnt[t] + 1u));   // +1 self loop
        }
        nb[t] = nodebase;
    }
    __syncthreads();
    for (unsigned j = beg + (unsigned)t; j < end; j += 256) {
        unsigned v = stage[j];
        unsigned pos = atomicAdd(&nb[v & (BKT_N - 1u)], 1u);
        csr[pos] = (int)(v >> BKT_SHIFT);
    }
}

// ------- GEMM1 (LDS-staged x-tile, 8-row blocking): xW1h = fp16((x@W1)*dinv)
__global__ __launch_bounds__(256) void k_gemm1(
        const float* __restrict__ x, const float* __restrict__ W1,
        const float* __restrict__ dinv, __half* __restrict__ xW1h) {
    __shared__ float W1s[IN_DIM * H1];      // 16 KB
    __shared__ float xs[G1_ROWS * IN_DIM];  // 32 KB
    int tid = threadIdx.x;
    for (int i = tid; i < IN_DIM * H1; i += 256) W1s[i] = W1[i];
    // coalesced x-tile stage: 2048 float4, 8 per thread
    int row0 = blockIdx.x * G1_ROWS;
    const float4* src4 = reinterpret_cast<const float4*>(x + (size_t)row0 * IN_DIM);
    float4* xs4 = reinterpret_cast<float4*>(xs);
#pragma unroll
    for (int k = 0; k < 8; ++k) xs4[tid + k * 256] = src4[tid + k * 256];
    __syncthreads();
    int c = tid & 31, g = tid >> 5;   // 8 groups x 8 rows
    float acc[8] = {0.f, 0.f, 0.f, 0.f, 0.f, 0.f, 0.f, 0.f};
    for (int j = 0; j < IN_DIM / 4; ++j) {
        float w0 = W1s[(4 * j + 0) * H1 + c];
        float w1 = W1s[(4 * j + 1) * H1 + c];
        float w2 = W1s[(4 * j + 2) * H1 + c];
        float w3 = W1s[(4 * j + 3) * H1 + c];
#pragma unroll
        for (int r = 0; r < 8; ++r) {
            float4 a = *reinterpret_cast<const float4*>(&xs[((g * 8 + r) << 7) + 4 * j]);
            acc[r] += a.x * w0 + a.y * w1 + a.z * w2 + a.w * w3;
        }
    }
#pragma unroll
    for (int r = 0; r < 8; ++r) {
        int row = row0 + g * 8 + r;
        xW1h[(size_t)row * H1 + c] = __float2half(acc[r] * dinv[row]);
    }
}

// ------- gather layer 1 FUSED with GEMM2 (packed hfma2 main loop) -------
// 16 edge slots x 4 lanes; 64-edge chunks, depth-4 fp16 accumulation
// (identical scheme to k_gather2_final), f32 flush per chunk. After the
// xor-reduce every lane holds the full agg1 row; fused GEMM2 epilogue:
// lane = output column, rel via 32 compile-time shfls.
__global__ __launch_bounds__(256) void k_gather1_gemm2(
        const unsigned* __restrict__ row_ptr, const unsigned* __restrict__ rend,
        const int* __restrict__ csr, const __half* __restrict__ xW1h,
        const float* __restrict__ dinv, const float* __restrict__ b1,
        const float* __restrict__ W2, __half* __restrict__ h2h) {
    int wave = threadIdx.x >> 6;
    int lane = threadIdx.x & 63;
    int q = lane >> 2, t = lane & 3;    // slot q in [0,16), features 8t..8t+7
    int d = blockIdx.x * 4 + wave;
    unsigned beg = row_ptr[d], end = rend[d];
    float acc[8] = {0.f, 0.f, 0.f, 0.f, 0.f, 0.f, 0.f, 0.f};
    const __half2 one2  = __float2half2_rn(1.0f);
    const __half2 zero2 = __float2half2_rn(0.0f);
    for (unsigned base = beg; base < end; base += 64) {
        __half2 hacc[4] = {zero2, zero2, zero2, zero2};
#pragma unroll
        for (int it = 0; it < 2; ++it) {
            unsigned j0 = base + (unsigned)(it * 32) + (unsigned)q;
            unsigned j1 = j0 + 16u;
            int     s0 = (j0 < end) ? csr[j0] : 0;
            __half2 m0 = (j0 < end) ? one2 : zero2;
            int     s1 = (j1 < end) ? csr[j1] : 0;
            __half2 m1 = (j1 < end) ? one2 : zero2;
            float4 raw0 = *reinterpret_cast<const float4*>(xW1h + (size_t)s0 * H1 + 8 * t);
            float4 raw1 = *reinterpret_cast<const float4*>(xW1h + (size_t)s1 * H1 + 8 * t);
            const __half2* h0 = reinterpret_cast<const __half2*>(&raw0);
            const __half2* h1 = reinterpret_cast<const __half2*>(&raw1);
#pragma unroll
            for (int i = 0; i < 4; ++i) {
                hacc[i] = __hfma2(h0[i], m0, hacc[i]);
                hacc[i] = __hfma2(h1[i], m1, hacc[i]);
            }
        }
#pragma unroll
        for (int i = 0; i < 4; ++i) {
            float2 f = __half22float2(hacc[i]);
            acc[2 * i]     += f.x;
            acc[2 * i + 1] += f.y;
        }
    }
#pragma unroll
    for (int m = 4; m <= 32; m <<= 1)
#pragma unroll
        for (int i = 0; i < 8; ++i)
            acc[i] += __shfl_xor(acc[i], m, 64);
    // ---- fused GEMM2 epilogue (all lanes active) ----
    float dv = dinv[d];
    float4 sraw = *reinterpret_cast<const float4*>(xW1h + (size_t)d * H1 + 8 * t);
    const __half2* sh = reinterpret_cast<const __half2*>(&sraw);
    float rel[8];
#pragma unroll
    for (int i = 0; i < 4; ++i) {
        float2 f = __half22float2(sh[i]);
        rel[2 * i]     = fmaxf((acc[2 * i]     + f.x) * dv + b1[8 * t + 2 * i],     0.f);
        rel[2 * i + 1] = fmaxf((acc[2 * i + 1] + f.y) * dv + b1[8 * t + 2 * i + 1], 0.f);
    }
    // W2 column c = lane (loaded after the gather loop to limit live VGPRs)
    float h2 = 0.f;
#pragma unroll
    for (int k = 0; k < H1; ++k) {
        float w = W2[k * H2 + lane];                 // coalesced, L1/L2-hot
        h2 += __shfl(rel[k & 7], k >> 3, 64) * w;    // src lane t == k>>3
    }
    h2h[(size_t)d * H2 + lane] = __float2half(h2 * dv);
}

// ------- gather layer 2 FUSED with readout (fp16 rows, packed hfma2) ------
__global__ __launch_bounds__(256) void k_gather2_final(
        const unsigned* __restrict__ row_ptr, const unsigned* __restrict__ rend,
        const int* __restrict__ csr, const __half* __restrict__ h2h,
        const float* __restrict__ dinv, const float* __restrict__ b2,
        const float* __restrict__ Wout, double* __restrict__ partial2) {
    int wave = threadIdx.x >> 6;
    int lane = threadIdx.x & 63;
    int o = lane >> 3, t = lane & 7;   // slot o in [0,8), features 8t..8t+7
    int d = blockIdx.x * 4 + wave;
    unsigned beg = row_ptr[d], end = rend[d];
    float acc[8] = {0.f, 0.f, 0.f, 0.f, 0.f, 0.f, 0.f, 0.f};
    const __half2 one2  = __float2half2_rn(1.0f);
    const __half2 zero2 = __float2half2_rn(0.0f);
    for (unsigned base = beg; base < end; base += 32) {
        __half2 hacc[4] = {zero2, zero2, zero2, zero2};
#pragma unroll
        for (int it = 0; it < 2; ++it) {
            unsigned j0 = base + (unsigned)(it * 16) + (unsigned)o;
            unsigned j1 = j0 + 8u;
            int     s0 = (j0 < end) ? csr[j0] : 0;
            __half2 m0 = (j0 < end) ? one2 : zero2;
            int     s1 = (j1 < end) ? csr[j1] : 0;
            __half2 m1 = (j1 < end) ? one2 : zero2;
            float4 raw0 = *reinterpret_cast<const float4*>(h2h + (size_t)s0 * H2 + 8 * t);
            float4 raw1 = *reinterpret_cast<const float4*>(h2h + (size_t)s1 * H2 + 8 * t);
            const __half2* h0 = reinterpret_cast<const __half2*>(&raw0);
            const __half2* h1 = reinterpret_cast<const __half2*>(&raw1);
#pragma unroll
            for (int i = 0; i < 4; ++i) {
                hacc[i] = __hfma2(h0[i], m0, hacc[i]);
                hacc[i] = __hfma2(h1[i], m1, hacc[i]);
            }
        }
#pragma unroll
        for (int i = 0; i < 4; ++i) {
            float2 f = __half22float2(hacc[i]);
            acc[2 * i]     += f.x;
            acc[2 * i + 1] += f.y;
        }
    }
#pragma unroll
    for (int m = 8; m <= 32; m <<= 1)
#pragma unroll
        for (int i = 0; i < 8; ++i)
            acc[i] += __shfl_xor(acc[i], m, 64);
    float dv = dinv[d];
    float4 sraw = *reinterpret_cast<const float4*>(h2h + (size_t)d * H2 + 8 * t);
    const __half2* sh = reinterpret_cast<const __half2*>(&sraw);
    float4 bb0 = *reinterpret_cast<const float4*>(b2 + 8 * t);
    float4 bb1 = *reinterpret_cast<const float4*>(b2 + 8 * t + 4);
    const float* wrow = Wout + (size_t)(d % NPB) * H2 + 8 * t;
    float4 ww0 = *reinterpret_cast<const float4*>(wrow);
    float4 ww1 = *reinterpret_cast<const float4*>(wrow + 4);
    float self[8];
#pragma unroll
    for (int i = 0; i < 4; ++i) {
        float2 f = __half22float2(sh[i]);
        self[2 * i] = f.x; self[2 * i + 1] = f.y;
    }
    float bbv[8] = {bb0.x, bb0.y, bb0.z, bb0.w, bb1.x, bb1.y, bb1.z, bb1.w};
    float wwv[8] = {ww0.x, ww0.y, ww0.z, ww0.w, ww1.x, ww1.y, ww1.z, ww1.w};
    double dval = 0.0;
#pragma unroll
    for (int i = 0; i < 8; ++i)
        dval += (double)(fmaxf((acc[i] + self[i]) * dv + bbv[i], 0.f) * wwv[i]);
    dval += __shfl_down(dval, 4, 64);
    dval += __shfl_down(dval, 2, 64);
    dval += __shfl_down(dval, 1, 64);
    __shared__ double sdbl[4];
    if (lane == 0) sdbl[wave] = dval;
    __syncthreads();
    if (threadIdx.x == 0)
        partial2[blockIdx.x] = (sdbl[0] + sdbl[1]) + (sdbl[2] + sdbl[3]);
}

// ------- final reduce: out[b] = sum of partial2[b*2500 .. ) + bout -------
__global__ __launch_bounds__(256) void k_reduce(
        const double* __restrict__ partial2, const float* __restrict__ bout,
        float* __restrict__ out) {
    int b = blockIdx.x;
    int tid = threadIdx.x;
    double acc = 0.0;
    for (int i = tid; i < BLK_PER_BATCH; i += 256)
        acc += partial2[b * BLK_PER_BATCH + i];
    for (int off = 32; off; off >>= 1) acc += __shfl_down(acc, off, 64);
    __shared__ double sred[4];
    if ((tid & 63) == 0) sred[tid >> 6] = acc;
    __syncthreads();
    if (tid == 0)
        out[b] = (float)(((sred[0] + sred[1]) + (sred[2] + sred[3])) + (double)bout[0]);
}

extern "C" void kernel_launch(void* const* d_in, const int* in_sizes, int n_in,
                              void* d_out, int out_size, void* d_ws, size_t ws_size,
                              hipStream_t stream) {
    const float* x    = (const float*)d_in[0];
    const int*   ei   = (const int*)d_in[1];    // int32 (JAX x64 disabled)
    const float* W1   = (const float*)d_in[2];
    const float* b1   = (const float*)d_in[3];
    const float* W2   = (const float*)d_in[4];
    const float* b2   = (const float*)d_in[5];
    const float* Wout = (const float*)d_in[6];
    const float* bout = (const float*)d_in[7];
    float* out = (float*)d_out;

    // workspace layout — no aliasing, total ~40 MB
    constexpr size_t STATIC_SZ = (size_t)NBKT * SBKT_CAP;   // 2.885M entries
    char* ws = (char*)d_ws;
    size_t off = 0;
    int*      csr     = (int*)(ws + off);      off += STATIC_SZ * 4;             // 11.54 MB
    unsigned* stage   = (unsigned*)(ws + off); off += STATIC_SZ * 4;             // 11.54 MB
    __half*   xW1h    = (__half*)(ws + off);   off += (size_t)N_NODES * H1 * 2;  // 5.12 MB
    __half*   h2h     = (__half*)(ws + off);   off += (size_t)N_NODES * H2 * 2;  // 10.24 MB
    unsigned* row_ptr = (unsigned*)(ws + off); off += (size_t)N_NODES * 4;       // 0.32 MB
    unsigned* rend    = (unsigned*)(ws + off); off += (size_t)N_NODES * 4;       // 0.32 MB
    float*    dinv    = (float*)(ws + off);    off += (size_t)N_NODES * 4;       // 0.32 MB
    unsigned* bbump   = (unsigned*)(ws + off); off += (size_t)NBKT * BBSTRIDE * 4; // 20 KB
    double*   partial2= (double*)(ws + off);   off += (size_t)G2_BLOCKS * 8;     // 0.16 MB
    (void)ws_size; (void)in_sizes; (void)n_in; (void)out_size;

    const int B = 256;
    k_initb<<<(NBKT + B - 1) / B, B, 0, stream>>>(bbump);
    k_binfill<<<BF_BLOCKS, BF_THREADS, 0, stream>>>(ei, bbump, stage);
    k_place<<<NBKT, B, 0, stream>>>(bbump, stage, csr, row_ptr, rend, dinv);

    k_gemm1<<<G1_BLOCKS, B, 0, stream>>>(x, W1, dinv, xW1h);
    k_gather1_gemm2<<<N_NODES / 4, B, 0, stream>>>(row_ptr, rend, csr, xW1h, dinv, b1, W2, h2h);
    k_gather2_final<<<G2_BLOCKS, B, 0, stream>>>(row_ptr, rend, csr, h2h, dinv, b2, Wout, partial2);

    k_reduce<<<NB, B, 0, stream>>>(partial2, bout, out);
}

// Round 18
// 181.881 us; speedup vs baseline: 1.0966x; 1.0966x over previous
//
#include <hip/hip_runtime.h>
#include <hip/hip_fp16.h>

// Problem constants (match reference)
constexpr int   N_NODES = 80000;
constexpr int   N_EDGE  = 2560000;
constexpr int   IN_DIM  = 128;
constexpr int   H1      = 32;
constexpr int   H2      = 64;
constexpr int   NPB     = 10000;   // nodes per batch
constexpr int   NB      = 8;       // batches
constexpr int   G2_BLOCKS = N_NODES / 4;        // 20000 (4 nodes per block)
constexpr int   BLK_PER_BATCH = G2_BLOCKS / NB; // 2500

// binned-fill parameters (static bucket capacity, 256 nodes per bucket)
constexpr int   BKT_SHIFT = 8;                       // 256 nodes per bucket
constexpr int   BKT_N     = 1 << BKT_SHIFT;          // 256
constexpr int   NBKT      = (N_NODES + BKT_N - 1) >> BKT_SHIFT;  // 313
constexpr int   BBSTRIDE  = 16;                      // pad bucket counters to 64 B
constexpr unsigned SBKT_CAP = 9216;                  // mean 8192 + ~11 sigma
constexpr int   BF_EPB    = 8192;                    // edges per binfill block
constexpr int   BF_BLOCKS = (N_EDGE + BF_EPB - 1) / BF_EPB;  // 313
constexpr int   BF_THREADS = 512;

// gemm1 tile parameters
constexpr int   G1_ROWS   = 64;                      // rows per block tile
constexpr int   G1_BLOCKS = N_NODES / G1_ROWS;       // 1250

// ---------------- seed bucket bumps with static bases ----------------
__global__ void k_initb(unsigned* __restrict__ bbump) {
    int i = blockIdx.x * blockDim.x + threadIdx.x;
    if (i < NBKT) bbump[i * BBSTRIDE] = (unsigned)i * SBKT_CAP;
}

// ------- binned fill: stage[pos] = (src<<8)|d_local, dense per bucket ------
__global__ __launch_bounds__(BF_THREADS) void k_binfill(
        const int* __restrict__ ei, unsigned* __restrict__ bbump,
        unsigned* __restrict__ stage) {
    __shared__ unsigned hist[NBKT];
    __shared__ unsigned base[NBKT];
    int t = threadIdx.x;
    int e0 = blockIdx.x * BF_EPB;
    int e1 = min(e0 + BF_EPB, N_EDGE);
    for (int i = t; i < NBKT; i += BF_THREADS) hist[i] = 0u;
    __syncthreads();
    for (int e = e0 + t; e < e1; e += BF_THREADS) {
        int d = ei[N_EDGE + e];
        atomicAdd(&hist[d >> BKT_SHIFT], 1u);
    }
    __syncthreads();
    for (int i = t; i < NBKT; i += BF_THREADS) {
        unsigned h = hist[i];
        base[i] = h ? atomicAdd(&bbump[i * BBSTRIDE], h) : 0u;
        hist[i] = 0u;
    }
    __syncthreads();
    for (int e = e0 + t; e < e1; e += BF_THREADS) {
        int s = ei[e];
        int d = ei[N_EDGE + e];
        int bkt = d >> BKT_SHIFT;
        unsigned lp = atomicAdd(&hist[bkt], 1u);
        unsigned pos = base[bkt] + lp;
        if (pos < (unsigned)(bkt + 1) * SBKT_CAP)   // capacity guard (never hit)
            stage[pos] = ((unsigned)s << BKT_SHIFT) | (unsigned)(d & (BKT_N - 1));
    }
}

// ------- place: per-bucket degrees (LDS) -> row_ptr, rend, dinv, csr -------
__global__ __launch_bounds__(256) void k_place(
        const unsigned* __restrict__ bbump, const unsigned* __restrict__ stage,
        int* __restrict__ csr, unsigned* __restrict__ row_ptr,
        unsigned* __restrict__ rend, float* __restrict__ dinv) {
    __shared__ unsigned cnt[BKT_N];
    __shared__ unsigned sc[BKT_N];
    __shared__ unsigned nb[BKT_N];
    int b = blockIdx.x;
    int t = threadIdx.x;              // 256 threads == BKT_N
    unsigned beg = (unsigned)b * SBKT_CAP;
    unsigned end = min(bbump[b * BBSTRIDE], (unsigned)(b + 1) * SBKT_CAP);
    cnt[t] = 0u;
    __syncthreads();
    for (unsigned j = beg + (unsigned)t; j < end; j += 256)
        atomicAdd(&cnt[stage[j] & (BKT_N - 1u)], 1u);
    __syncthreads();
    sc[t] = cnt[t];
    for (int ofs = 1; ofs < BKT_N; ofs <<= 1) {
        __syncthreads();
        unsigned u = (t >= ofs) ? sc[t - ofs] : 0u;
        __syncthreads();
        sc[t] += u;
    }
    __syncthreads();
    {
        unsigned nodebase = beg + sc[t] - cnt[t];
        int node = (b << BKT_SHIFT) + t;
        if (node < N_NODES) {
            row_ptr[node] = nodebase;
            rend[node]    = nodebase + cnt[t];
            dinv[node] = rsqrtf((float)(cnt[t] + 1u));   // +1 self loop
        }
        nb[t] = nodebase;
    }
    __syncthreads();
    for (unsigned j = beg + (unsigned)t; j < end; j += 256) {
        unsigned v = stage[j];
        unsigned pos = atomicAdd(&nb[v & (BKT_N - 1u)], 1u);
        csr[pos] = (int)(v >> BKT_SHIFT);
    }
}

// ------- GEMM1 (LDS-staged x-tile, 8-row blocking): xW1h = fp16((x@W1)*dinv)
__global__ __launch_bounds__(256) void k_gemm1(
        const float* __restrict__ x, const float* __restrict__ W1,
        const float* __restrict__ dinv, __half* __restrict__ xW1h) {
    __shared__ float W1s[IN_DIM * H1];      // 16 KB
    __shared__ float xs[G1_ROWS * IN_DIM];  // 32 KB
    int tid = threadIdx.x;
    for (int i = tid; i < IN_DIM * H1; i += 256) W1s[i] = W1[i];
    // coalesced x-tile stage: 2048 float4, 8 per thread
    int row0 = blockIdx.x * G1_ROWS;
    const float4* src4 = reinterpret_cast<const float4*>(x + (size_t)row0 * IN_DIM);
    float4* xs4 = reinterpret_cast<float4*>(xs);
#pragma unroll
    for (int k = 0; k < 8; ++k) xs4[tid + k * 256] = src4[tid + k * 256];
    __syncthreads();
    int c = tid & 31, g = tid >> 5;   // 8 groups x 8 rows
    float acc[8] = {0.f, 0.f, 0.f, 0.f, 0.f, 0.f, 0.f, 0.f};
    for (int j = 0; j < IN_DIM / 4; ++j) {
        float w0 = W1s[(4 * j + 0) * H1 + c];
        float w1 = W1s[(4 * j + 1) * H1 + c];
        float w2 = W1s[(4 * j + 2) * H1 + c];
        float w3 = W1s[(4 * j + 3) * H1 + c];
#pragma unroll
        for (int r = 0; r < 8; ++r) {
            float4 a = *reinterpret_cast<const float4*>(&xs[((g * 8 + r) << 7) + 4 * j]);
            acc[r] += a.x * w0 + a.y * w1 + a.z * w2 + a.w * w3;
        }
    }
#pragma unroll
    for (int r = 0; r < 8; ++r) {
        int row = row0 + g * 8 + r;
        xW1h[(size_t)row * H1 + c] = __float2half(acc[r] * dinv[row]);
    }
}

// ------- gather layer 1 FUSED with GEMM2 — 2 nodes per wave -------
// Half-wave (32 lanes) per node: 8 edge slots x 4 feature-lanes. 32-edge
// chunks, depth-4 fp16 hfma2 accumulation, f32 flush per chunk. Reduce is
// xor 4/8/16 (stays within the half). Fused GEMM2: each lane computes 2
// output columns (c, c+32) of its half's node. Amortizes the per-node
// epilogue that round-17 counters showed dominating VALU issue.
__global__ __launch_bounds__(256) void k_gather1_gemm2(
        const unsigned* __restrict__ row_ptr, const unsigned* __restrict__ rend,
        const int* __restrict__ csr, const __half* __restrict__ xW1h,
        const float* __restrict__ dinv, const float* __restrict__ b1,
        const float* __restrict__ W2, __half* __restrict__ h2h) {
    int wave = threadIdx.x >> 6;
    int lane = threadIdx.x & 63;
    int h = lane >> 5;                  // node half (0/1)
    int q = (lane >> 2) & 7;            // edge slot 0..7
    int t = lane & 3;                   // feature quad: features 8t..8t+7
    int d = blockIdx.x * 8 + wave * 2 + h;
    unsigned beg = row_ptr[d], end = rend[d];
    float acc[8] = {0.f, 0.f, 0.f, 0.f, 0.f, 0.f, 0.f, 0.f};
    const __half2 one2  = __float2half2_rn(1.0f);
    const __half2 zero2 = __float2half2_rn(0.0f);
    for (unsigned base = beg; base < end; base += 32) {
        __half2 hacc[4] = {zero2, zero2, zero2, zero2};
#pragma unroll
        for (int it = 0; it < 2; ++it) {
            unsigned j0 = base + (unsigned)(it * 16) + (unsigned)q;
            unsigned j1 = j0 + 8u;
            int     s0 = (j0 < end) ? csr[j0] : 0;
            __half2 m0 = (j0 < end) ? one2 : zero2;
            int     s1 = (j1 < end) ? csr[j1] : 0;
            __half2 m1 = (j1 < end) ? one2 : zero2;
            float4 raw0 = *reinterpret_cast<const float4*>(xW1h + (size_t)s0 * H1 + 8 * t);
            float4 raw1 = *reinterpret_cast<const float4*>(xW1h + (size_t)s1 * H1 + 8 * t);
            const __half2* h0 = reinterpret_cast<const __half2*>(&raw0);
            const __half2* h1 = reinterpret_cast<const __half2*>(&raw1);
#pragma unroll
            for (int i = 0; i < 4; ++i) {
                hacc[i] = __hfma2(h0[i], m0, hacc[i]);
                hacc[i] = __hfma2(h1[i], m1, hacc[i]);
            }
        }
#pragma unroll
        for (int i = 0; i < 4; ++i) {
            float2 f = __half22float2(hacc[i]);
            acc[2 * i]     += f.x;
            acc[2 * i + 1] += f.y;
        }
    }
    // reduce across the 8 edge slots (stays within each 32-lane half)
#pragma unroll
    for (int m = 4; m <= 16; m <<= 1)
#pragma unroll
        for (int i = 0; i < 8; ++i)
            acc[i] += __shfl_xor(acc[i], m, 64);
    // ---- fused GEMM2 epilogue (all lanes active; 2 cols per lane) ----
    float dv = dinv[d];
    float4 sraw = *reinterpret_cast<const float4*>(xW1h + (size_t)d * H1 + 8 * t);
    const __half2* sh = reinterpret_cast<const __half2*>(&sraw);
    float rel[8];
#pragma unroll
    for (int i = 0; i < 4; ++i) {
        float2 f = __half22float2(sh[i]);
        rel[2 * i]     = fmaxf((acc[2 * i]     + f.x) * dv + b1[8 * t + 2 * i],     0.f);
        rel[2 * i + 1] = fmaxf((acc[2 * i + 1] + f.y) * dv + b1[8 * t + 2 * i + 1], 0.f);
    }
    int c = lane & 31;
    float h2a = 0.f, h2b = 0.f;
#pragma unroll
    for (int k = 0; k < H1; ++k) {
        int src = (lane & 32) | (k >> 3);            // q=0, t=k>>3 in same half
        float r = __shfl(rel[k & 7], src, 64);
        h2a += r * W2[k * H2 + c];                   // coalesced, L1/L2-hot
        h2b += r * W2[k * H2 + c + 32];
    }
    h2h[(size_t)d * H2 + c]      = __float2half(h2a * dv);
    h2h[(size_t)d * H2 + c + 32] = __float2half(h2b * dv);
}

// ------- gather layer 2 FUSED with readout (fp16 rows, packed hfma2) ------
__global__ __launch_bounds__(256) void k_gather2_final(
        const unsigned* __restrict__ row_ptr, const unsigned* __restrict__ rend,
        const int* __restrict__ csr, const __half* __restrict__ h2h,
        const float* __restrict__ dinv, const float* __restrict__ b2,
        const float* __restrict__ Wout, double* __restrict__ partial2) {
    int wave = threadIdx.x >> 6;
    int lane = threadIdx.x & 63;
    int o = lane >> 3, t = lane & 7;   // slot o in [0,8), features 8t..8t+7
    int d = blockIdx.x * 4 + wave;
    unsigned beg = row_ptr[d], end = rend[d];
    float acc[8] = {0.f, 0.f, 0.f, 0.f, 0.f, 0.f, 0.f, 0.f};
    const __half2 one2  = __float2half2_rn(1.0f);
    const __half2 zero2 = __float2half2_rn(0.0f);
    for (unsigned base = beg; base < end; base += 32) {
        __half2 hacc[4] = {zero2, zero2, zero2, zero2};
#pragma unroll
        for (int it = 0; it < 2; ++it) {
            unsigned j0 = base + (unsigned)(it * 16) + (unsigned)o;
            unsigned j1 = j0 + 8u;
            int     s0 = (j0 < end) ? csr[j0] : 0;
            __half2 m0 = (j0 < end) ? one2 : zero2;
            int     s1 = (j1 < end) ? csr[j1] : 0;
            __half2 m1 = (j1 < end) ? one2 : zero2;
            float4 raw0 = *reinterpret_cast<const float4*>(h2h + (size_t)s0 * H2 + 8 * t);
            float4 raw1 = *reinterpret_cast<const float4*>(h2h + (size_t)s1 * H2 + 8 * t);
            const __half2* h0 = reinterpret_cast<const __half2*>(&raw0);
            const __half2* h1 = reinterpret_cast<const __half2*>(&raw1);
#pragma unroll
            for (int i = 0; i < 4; ++i) {
                hacc[i] = __hfma2(h0[i], m0, hacc[i]);
                hacc[i] = __hfma2(h1[i], m1, hacc[i]);
            }
        }
#pragma unroll
        for (int i = 0; i < 4; ++i) {
            float2 f = __half22float2(hacc[i]);
            acc[2 * i]     += f.x;
            acc[2 * i + 1] += f.y;
        }
    }
#pragma unroll
    for (int m = 8; m <= 32; m <<= 1)
#pragma unroll
        for (int i = 0; i < 8; ++i)
            acc[i] += __shfl_xor(acc[i], m, 64);
    float dv = dinv[d];
    float4 sraw = *reinterpret_cast<const float4*>(h2h + (size_t)d * H2 + 8 * t);
    const __half2* sh = reinterpret_cast<const __half2*>(&sraw);
    float4 bb0 = *reinterpret_cast<const float4*>(b2 + 8 * t);
    float4 bb1 = *reinterpret_cast<const float4*>(b2 + 8 * t + 4);
    const float* wrow = Wout + (size_t)(d % NPB) * H2 + 8 * t;
    float4 ww0 = *reinterpret_cast<const float4*>(wrow);
    float4 ww1 = *reinterpret_cast<const float4*>(wrow + 4);
    float self[8];
#pragma unroll
    for (int i = 0; i < 4; ++i) {
        float2 f = __half22float2(sh[i]);
        self[2 * i] = f.x; self[2 * i + 1] = f.y;
    }
    float bbv[8] = {bb0.x, bb0.y, bb0.z, bb0.w, bb1.x, bb1.y, bb1.z, bb1.w};
    float wwv[8] = {ww0.x, ww0.y, ww0.z, ww0.w, ww1.x, ww1.y, ww1.z, ww1.w};
    double dval = 0.0;
#pragma unroll
    for (int i = 0; i < 8; ++i)
        dval += (double)(fmaxf((acc[i] + self[i]) * dv + bbv[i], 0.f) * wwv[i]);
    dval += __shfl_down(dval, 4, 64);
    dval += __shfl_down(dval, 2, 64);
    dval += __shfl_down(dval, 1, 64);
    __shared__ double sdbl[4];
    if (lane == 0) sdbl[wave] = dval;
    __syncthreads();
    if (threadIdx.x == 0)
        partial2[blockIdx.x] = (sdbl[0] + sdbl[1]) + (sdbl[2] + sdbl[3]);
}

// ------- final reduce: out[b] = sum of partial2[b*2500 .. ) + bout -------
__global__ __launch_bounds__(256) void k_reduce(
        const double* __restrict__ partial2, const float* __restrict__ bout,
        float* __restrict__ out) {
    int b = blockIdx.x;
    int tid = threadIdx.x;
    double acc = 0.0;
    for (int i = tid; i < BLK_PER_BATCH; i += 256)
        acc += partial2[b * BLK_PER_BATCH + i];
    for (int off = 32; off; off >>= 1) acc += __shfl_down(acc, off, 64);
    __shared__ double sred[4];
    if ((tid & 63) == 0) sred[tid >> 6] = acc;
    __syncthreads();
    if (tid == 0)
        out[b] = (float)(((sred[0] + sred[1]) + (sred[2] + sred[3])) + (double)bout[0]);
}

extern "C" void kernel_launch(void* const* d_in, const int* in_sizes, int n_in,
                              void* d_out, int out_size, void* d_ws, size_t ws_size,
                              hipStream_t stream) {
    const float* x    = (const float*)d_in[0];
    const int*   ei   = (const int*)d_in[1];    // int32 (JAX x64 disabled)
    const float* W1   = (const float*)d_in[2];
    const float* b1   = (const float*)d_in[3];
    const float* W2   = (const float*)d_in[4];
    const float* b2   = (const float*)d_in[5];
    const float* Wout = (const float*)d_in[6];
    const float* bout = (const float*)d_in[7];
    float* out = (float*)d_out;

    // workspace layout — no aliasing, total ~40 MB
    constexpr size_t STATIC_SZ = (size_t)NBKT * SBKT_CAP;   // 2.885M entries
    char* ws = (char*)d_ws;
    size_t off = 0;
    int*      csr     = (int*)(ws + off);      off += STATIC_SZ * 4;             // 11.54 MB
    unsigned* stage   = (unsigned*)(ws + off); off += STATIC_SZ * 4;             // 11.54 MB
    __half*   xW1h    = (__half*)(ws + off);   off += (size_t)N_NODES * H1 * 2;  // 5.12 MB
    __half*   h2h     = (__half*)(ws + off);   off += (size_t)N_NODES * H2 * 2;  // 10.24 MB
    unsigned* row_ptr = (unsigned*)(ws + off); off += (size_t)N_NODES * 4;       // 0.32 MB
    unsigned* rend    = (unsigned*)(ws + off); off += (size_t)N_NODES * 4;       // 0.32 MB
    float*    dinv    = (float*)(ws + off);    off += (size_t)N_NODES * 4;       // 0.32 MB
    unsigned* bbump   = (unsigned*)(ws + off); off += (size_t)NBKT * BBSTRIDE * 4; // 20 KB
    double*   partial2= (double*)(ws + off);   off += (size_t)G2_BLOCKS * 8;     // 0.16 MB
    (void)ws_size; (void)in_sizes; (void)n_in; (void)out_size;

    const int B = 256;
    k_initb<<<(NBKT + B - 1) / B, B, 0, stream>>>(bbump);
    k_binfill<<<BF_BLOCKS, BF_THREADS, 0, stream>>>(ei, bbump, stage);
    k_place<<<NBKT, B, 0, stream>>>(bbump, stage, csr, row_ptr, rend, dinv);

    k_gemm1<<<G1_BLOCKS, B, 0, stream>>>(x, W1, dinv, xW1h);
    k_gather1_gemm2<<<N_NODES / 8, B, 0, stream>>>(row_ptr, rend, csr, xW1h, dinv, b1, W2, h2h);
    k_gather2_final<<<G2_BLOCKS, B, 0, stream>>>(row_ptr, rend, csr, h2h, dinv, b2, Wout, partial2);

    k_reduce<<<NB, B, 0, stream>>>(partial2, bout, out);
}

// Round 19
// 175.744 us; speedup vs baseline: 1.1349x; 1.0349x over previous
//
#include <hip/hip_runtime.h>
#include <hip/hip_fp16.h>

// Problem constants (match reference)
constexpr int   N_NODES = 80000;
constexpr int   N_EDGE  = 2560000;
constexpr int   IN_DIM  = 128;
constexpr int   H1      = 32;
constexpr int   H2      = 64;
constexpr int   NPB     = 10000;   // nodes per batch
constexpr int   NB      = 8;       // batches
constexpr int   G2_BLOCKS = N_NODES / 8;        // 10000 (8 nodes per block)
constexpr int   BLK_PER_BATCH = G2_BLOCKS / NB; // 1250

// binned-fill parameters (static bucket capacity, 256 nodes per bucket)
constexpr int   BKT_SHIFT = 8;                       // 256 nodes per bucket
constexpr int   BKT_N     = 1 << BKT_SHIFT;          // 256
constexpr int   NBKT      = (N_NODES + BKT_N - 1) >> BKT_SHIFT;  // 313
constexpr int   BBSTRIDE  = 16;                      // pad bucket counters to 64 B
constexpr unsigned SBKT_CAP = 9216;                  // mean 8192 + ~11 sigma
constexpr int   BF_EPB    = 8192;                    // edges per binfill block
constexpr int   BF_BLOCKS = (N_EDGE + BF_EPB - 1) / BF_EPB;  // 313
constexpr int   BF_THREADS = 512;

// gemm1 tile parameters
constexpr int   G1_ROWS   = 64;                      // rows per block tile
constexpr int   G1_BLOCKS = N_NODES / G1_ROWS;       // 1250

// ---------------- seed bucket bumps with static bases ----------------
__global__ void k_initb(unsigned* __restrict__ bbump) {
    int i = blockIdx.x * blockDim.x + threadIdx.x;
    if (i < NBKT) bbump[i * BBSTRIDE] = (unsigned)i * SBKT_CAP;
}

// ------- binned fill: stage[pos] = (src<<8)|d_local, dense per bucket ------
__global__ __launch_bounds__(BF_THREADS) void k_binfill(
        const int* __restrict__ ei, unsigned* __restrict__ bbump,
        unsigned* __restrict__ stage) {
    __shared__ unsigned hist[NBKT];
    __shared__ unsigned base[NBKT];
    int t = threadIdx.x;
    int e0 = blockIdx.x * BF_EPB;
    int e1 = min(e0 + BF_EPB, N_EDGE);
    for (int i = t; i < NBKT; i += BF_THREADS) hist[i] = 0u;
    __syncthreads();
    for (int e = e0 + t; e < e1; e += BF_THREADS) {
        int d = ei[N_EDGE + e];
        atomicAdd(&hist[d >> BKT_SHIFT], 1u);
    }
    __syncthreads();
    for (int i = t; i < NBKT; i += BF_THREADS) {
        unsigned h = hist[i];
        base[i] = h ? atomicAdd(&bbump[i * BBSTRIDE], h) : 0u;
        hist[i] = 0u;
    }
    __syncthreads();
    for (int e = e0 + t; e < e1; e += BF_THREADS) {
        int s = ei[e];
        int d = ei[N_EDGE + e];
        int bkt = d >> BKT_SHIFT;
        unsigned lp = atomicAdd(&hist[bkt], 1u);
        unsigned pos = base[bkt] + lp;
        if (pos < (unsigned)(bkt + 1) * SBKT_CAP)   // capacity guard (never hit)
            stage[pos] = ((unsigned)s << BKT_SHIFT) | (unsigned)(d & (BKT_N - 1));
    }
}

// ------- place: per-bucket degrees (LDS) -> row_ptr, rend, dinv, csr -------
__global__ __launch_bounds__(256) void k_place(
        const unsigned* __restrict__ bbump, const unsigned* __restrict__ stage,
        int* __restrict__ csr, unsigned* __restrict__ row_ptr,
        unsigned* __restrict__ rend, float* __restrict__ dinv) {
    __shared__ unsigned cnt[BKT_N];
    __shared__ unsigned sc[BKT_N];
    __shared__ unsigned nb[BKT_N];
    int b = blockIdx.x;
    int t = threadIdx.x;              // 256 threads == BKT_N
    unsigned beg = (unsigned)b * SBKT_CAP;
    unsigned end = min(bbump[b * BBSTRIDE], (unsigned)(b + 1) * SBKT_CAP);
    cnt[t] = 0u;
    __syncthreads();
    for (unsigned j = beg + (unsigned)t; j < end; j += 256)
        atomicAdd(&cnt[stage[j] & (BKT_N - 1u)], 1u);
    __syncthreads();
    sc[t] = cnt[t];
    for (int ofs = 1; ofs < BKT_N; ofs <<= 1) {
        __syncthreads();
        unsigned u = (t >= ofs) ? sc[t - ofs] : 0u;
        __syncthreads();
        sc[t] += u;
    }
    __syncthreads();
    {
        unsigned nodebase = beg + sc[t] - cnt[t];
        int node = (b << BKT_SHIFT) + t;
        if (node < N_NODES) {
            row_ptr[node] = nodebase;
            rend[node]    = nodebase + cnt[t];
            dinv[node] = rsqrtf((float)(cnt[t] + 1u));   // +1 self loop
        }
        nb[t] = nodebase;
    }
    __syncthreads();
    for (unsigned j = beg + (unsigned)t; j < end; j += 256) {
        unsigned v = stage[j];
        unsigned pos = atomicAdd(&nb[v & (BKT_N - 1u)], 1u);
        csr[pos] = (int)(v >> BKT_SHIFT);
    }
}

// ------- GEMM1 (LDS-staged x-tile, 8-row blocking): xW1h = fp16((x@W1)*dinv)
__global__ __launch_bounds__(256) void k_gemm1(
        const float* __restrict__ x, const float* __restrict__ W1,
        const float* __restrict__ dinv, __half* __restrict__ xW1h) {
    __shared__ float W1s[IN_DIM * H1];      // 16 KB
    __shared__ float xs[G1_ROWS * IN_DIM];  // 32 KB
    int tid = threadIdx.x;
    for (int i = tid; i < IN_DIM * H1; i += 256) W1s[i] = W1[i];
    // coalesced x-tile stage: 2048 float4, 8 per thread
    int row0 = blockIdx.x * G1_ROWS;
    const float4* src4 = reinterpret_cast<const float4*>(x + (size_t)row0 * IN_DIM);
    float4* xs4 = reinterpret_cast<float4*>(xs);
#pragma unroll
    for (int k = 0; k < 8; ++k) xs4[tid + k * 256] = src4[tid + k * 256];
    __syncthreads();
    int c = tid & 31, g = tid >> 5;   // 8 groups x 8 rows
    float acc[8] = {0.f, 0.f, 0.f, 0.f, 0.f, 0.f, 0.f, 0.f};
    for (int j = 0; j < IN_DIM / 4; ++j) {
        float w0 = W1s[(4 * j + 0) * H1 + c];
        float w1 = W1s[(4 * j + 1) * H1 + c];
        float w2 = W1s[(4 * j + 2) * H1 + c];
        float w3 = W1s[(4 * j + 3) * H1 + c];
#pragma unroll
        for (int r = 0; r < 8; ++r) {
            float4 a = *reinterpret_cast<const float4*>(&xs[((g * 8 + r) << 7) + 4 * j]);
            acc[r] += a.x * w0 + a.y * w1 + a.z * w2 + a.w * w3;
        }
    }
#pragma unroll
    for (int r = 0; r < 8; ++r) {
        int row = row0 + g * 8 + r;
        xW1h[(size_t)row * H1 + c] = __float2half(acc[r] * dinv[row]);
    }
}

// ------- gather layer 1 FUSED with GEMM2 — 2 nodes per wave -------
__global__ __launch_bounds__(256) void k_gather1_gemm2(
        const unsigned* __restrict__ row_ptr, const unsigned* __restrict__ rend,
        const int* __restrict__ csr, const __half* __restrict__ xW1h,
        const float* __restrict__ dinv, const float* __restrict__ b1,
        const float* __restrict__ W2, __half* __restrict__ h2h) {
    int wave = threadIdx.x >> 6;
    int lane = threadIdx.x & 63;
    int h = lane >> 5;                  // node half (0/1)
    int q = (lane >> 2) & 7;            // edge slot 0..7
    int t = lane & 3;                   // feature quad: features 8t..8t+7
    int d = blockIdx.x * 8 + wave * 2 + h;
    unsigned beg = row_ptr[d], end = rend[d];
    float acc[8] = {0.f, 0.f, 0.f, 0.f, 0.f, 0.f, 0.f, 0.f};
    const __half2 one2  = __float2half2_rn(1.0f);
    const __half2 zero2 = __float2half2_rn(0.0f);
    for (unsigned base = beg; base < end; base += 32) {
        __half2 hacc[4] = {zero2, zero2, zero2, zero2};
#pragma unroll
        for (int it = 0; it < 2; ++it) {
            unsigned j0 = base + (unsigned)(it * 16) + (unsigned)q;
            unsigned j1 = j0 + 8u;
            int     s0 = (j0 < end) ? csr[j0] : 0;
            __half2 m0 = (j0 < end) ? one2 : zero2;
            int     s1 = (j1 < end) ? csr[j1] : 0;
            __half2 m1 = (j1 < end) ? one2 : zero2;
            float4 raw0 = *reinterpret_cast<const float4*>(xW1h + (size_t)s0 * H1 + 8 * t);
            float4 raw1 = *reinterpret_cast<const float4*>(xW1h + (size_t)s1 * H1 + 8 * t);
            const __half2* h0 = reinterpret_cast<const __half2*>(&raw0);
            const __half2* h1 = reinterpret_cast<const __half2*>(&raw1);
#pragma unroll
            for (int i = 0; i < 4; ++i) {
                hacc[i] = __hfma2(h0[i], m0, hacc[i]);
                hacc[i] = __hfma2(h1[i], m1, hacc[i]);
            }
        }
#pragma unroll
        for (int i = 0; i < 4; ++i) {
            float2 f = __half22float2(hacc[i]);
            acc[2 * i]     += f.x;
            acc[2 * i + 1] += f.y;
        }
    }
    // reduce across the 8 edge slots (stays within each 32-lane half)
#pragma unroll
    for (int m = 4; m <= 16; m <<= 1)
#pragma unroll
        for (int i = 0; i < 8; ++i)
            acc[i] += __shfl_xor(acc[i], m, 64);
    // ---- fused GEMM2 epilogue (all lanes active; 2 cols per lane) ----
    float dv = dinv[d];
    float4 sraw = *reinterpret_cast<const float4*>(xW1h + (size_t)d * H1 + 8 * t);
    const __half2* sh = reinterpret_cast<const __half2*>(&sraw);
    float rel[8];
#pragma unroll
    for (int i = 0; i < 4; ++i) {
        float2 f = __half22float2(sh[i]);
        rel[2 * i]     = fmaxf((acc[2 * i]     + f.x) * dv + b1[8 * t + 2 * i],     0.f);
        rel[2 * i + 1] = fmaxf((acc[2 * i + 1] + f.y) * dv + b1[8 * t + 2 * i + 1], 0.f);
    }
    int c = lane & 31;
    float h2a = 0.f, h2b = 0.f;
#pragma unroll
    for (int k = 0; k < H1; ++k) {
        int src = (lane & 32) | (k >> 3);            // q=0, t=k>>3 in same half
        float r = __shfl(rel[k & 7], src, 64);
        h2a += r * W2[k * H2 + c];                   // coalesced, L1/L2-hot
        h2b += r * W2[k * H2 + c + 32];
    }
    h2h[(size_t)d * H2 + c]      = __float2half(h2a * dv);
    h2h[(size_t)d * H2 + c + 32] = __float2half(h2b * dv);
}

// ------- gather layer 2 FUSED with readout — 2 nodes per wave -------
// Half-wave (32 lanes) per node: 4 edge slots x 8 feature-lanes. 16-edge
// chunks, depth-4 fp16 hfma2 accumulation (2 sub-iters x 2 loads), f32 flush
// per chunk. Reduce xor 8/16 within the half; epilogue once per wave serves
// two nodes; f32 dot then single double convert; t-reduce via shfl_down.
__global__ __launch_bounds__(256) void k_gather2_final(
        const unsigned* __restrict__ row_ptr, const unsigned* __restrict__ rend,
        const int* __restrict__ csr, const __half* __restrict__ h2h,
        const float* __restrict__ dinv, const float* __restrict__ b2,
        const float* __restrict__ Wout, double* __restrict__ partial2) {
    int wave = threadIdx.x >> 6;
    int lane = threadIdx.x & 63;
    int h = lane >> 5;                 // node half (0/1)
    int o = (lane >> 3) & 3;           // edge slot 0..3
    int t = lane & 7;                  // feature octet: features 8t..8t+7
    int d = blockIdx.x * 8 + wave * 2 + h;
    unsigned beg = row_ptr[d], end = rend[d];
    float acc[8] = {0.f, 0.f, 0.f, 0.f, 0.f, 0.f, 0.f, 0.f};
    const __half2 one2  = __float2half2_rn(1.0f);
    const __half2 zero2 = __float2half2_rn(0.0f);
    for (unsigned base = beg; base < end; base += 16) {
        __half2 hacc[4] = {zero2, zero2, zero2, zero2};
#pragma unroll
        for (int it = 0; it < 2; ++it) {
            unsigned j0 = base + (unsigned)(it * 8) + (unsigned)o;
            unsigned j1 = j0 + 4u;
            int     s0 = (j0 < end) ? csr[j0] : 0;
            __half2 m0 = (j0 < end) ? one2 : zero2;
            int     s1 = (j1 < end) ? csr[j1] : 0;
            __half2 m1 = (j1 < end) ? one2 : zero2;
            float4 raw0 = *reinterpret_cast<const float4*>(h2h + (size_t)s0 * H2 + 8 * t);
            float4 raw1 = *reinterpret_cast<const float4*>(h2h + (size_t)s1 * H2 + 8 * t);
            const __half2* h0 = reinterpret_cast<const __half2*>(&raw0);
            const __half2* h1 = reinterpret_cast<const __half2*>(&raw1);
#pragma unroll
            for (int i = 0; i < 4; ++i) {
                hacc[i] = __hfma2(h0[i], m0, hacc[i]);
                hacc[i] = __hfma2(h1[i], m1, hacc[i]);
            }
        }
#pragma unroll
        for (int i = 0; i < 4; ++i) {
            float2 f = __half22float2(hacc[i]);
            acc[2 * i]     += f.x;
            acc[2 * i + 1] += f.y;
        }
    }
    // reduce across the 4 edge slots (stays within each 32-lane half)
#pragma unroll
    for (int m = 8; m <= 16; m <<= 1)
#pragma unroll
        for (int i = 0; i < 8; ++i)
            acc[i] += __shfl_xor(acc[i], m, 64);
    // epilogue: each half's lanes t=0..7 cover 64 features (dup across o)
    float dv = dinv[d];
    float4 sraw = *reinterpret_cast<const float4*>(h2h + (size_t)d * H2 + 8 * t);
    const __half2* sh = reinterpret_cast<const __half2*>(&sraw);
    float4 bb0 = *reinterpret_cast<const float4*>(b2 + 8 * t);
    float4 bb1 = *reinterpret_cast<const float4*>(b2 + 8 * t + 4);
    const float* wrow = Wout + (size_t)(d % NPB) * H2 + 8 * t;
    float4 ww0 = *reinterpret_cast<const float4*>(wrow);
    float4 ww1 = *reinterpret_cast<const float4*>(wrow + 4);
    float self[8];
#pragma unroll
    for (int i = 0; i < 4; ++i) {
        float2 f = __half22float2(sh[i]);
        self[2 * i] = f.x; self[2 * i + 1] = f.y;
    }
    float bbv[8] = {bb0.x, bb0.y, bb0.z, bb0.w, bb1.x, bb1.y, bb1.z, bb1.w};
    float wwv[8] = {ww0.x, ww0.y, ww0.z, ww0.w, ww1.x, ww1.y, ww1.z, ww1.w};
    float fsum = 0.f;
#pragma unroll
    for (int i = 0; i < 8; ++i)
        fsum += fmaxf((acc[i] + self[i]) * dv + bbv[i], 0.f) * wwv[i];
    double dval = (double)fsum;
    // reduce over t = 0..7 (within o-group; dval duplicated across o)
    dval += __shfl_down(dval, 4, 64);
    dval += __shfl_down(dval, 2, 64);
    dval += __shfl_down(dval, 1, 64);
    __shared__ double sdbl[8];
    if ((lane & 31) == 0) sdbl[wave * 2 + h] = dval;
    __syncthreads();
    if (threadIdx.x == 0)
        partial2[blockIdx.x] = ((sdbl[0] + sdbl[1]) + (sdbl[2] + sdbl[3]))
                             + ((sdbl[4] + sdbl[5]) + (sdbl[6] + sdbl[7]));
}

// ------- final reduce: out[b] = sum of partial2[b*1250 .. ) + bout -------
__global__ __launch_bounds__(256) void k_reduce(
        const double* __restrict__ partial2, const float* __restrict__ bout,
        float* __restrict__ out) {
    int b = blockIdx.x;
    int tid = threadIdx.x;
    double acc = 0.0;
    for (int i = tid; i < BLK_PER_BATCH; i += 256)
        acc += partial2[b * BLK_PER_BATCH + i];
    for (int off = 32; off; off >>= 1) acc += __shfl_down(acc, off, 64);
    __shared__ double sred[4];
    if ((tid & 63) == 0) sred[tid >> 6] = acc;
    __syncthreads();
    if (tid == 0)
        out[b] = (float)(((sred[0] + sred[1]) + (sred[2] + sred[3])) + (double)bout[0]);
}

extern "C" void kernel_launch(void* const* d_in, const int* in_sizes, int n_in,
                              void* d_out, int out_size, void* d_ws, size_t ws_size,
                              hipStream_t stream) {
    const float* x    = (const float*)d_in[0];
    const int*   ei   = (const int*)d_in[1];    // int32 (JAX x64 disabled)
    const float* W1   = (const float*)d_in[2];
    const float* b1   = (const float*)d_in[3];
    const float* W2   = (const float*)d_in[4];
    const float* b2   = (const float*)d_in[5];
    const float* Wout = (const float*)d_in[6];
    const float* bout = (const float*)d_in[7];
    float* out = (float*)d_out;

    // workspace layout — no aliasing, total ~40 MB
    constexpr size_t STATIC_SZ = (size_t)NBKT * SBKT_CAP;   // 2.885M entries
    char* ws = (char*)d_ws;
    size_t off = 0;
    int*      csr     = (int*)(ws + off);      off += STATIC_SZ * 4;             // 11.54 MB
    unsigned* stage   = (unsigned*)(ws + off); off += STATIC_SZ * 4;             // 11.54 MB
    __half*   xW1h    = (__half*)(ws + off);   off += (size_t)N_NODES * H1 * 2;  // 5.12 MB
    __half*   h2h     = (__half*)(ws + off);   off += (size_t)N_NODES * H2 * 2;  // 10.24 MB
    unsigned* row_ptr = (unsigned*)(ws + off); off += (size_t)N_NODES * 4;       // 0.32 MB
    unsigned* rend    = (unsigned*)(ws + off); off += (size_t)N_NODES * 4;       // 0.32 MB
    float*    dinv    = (float*)(ws + off);    off += (size_t)N_NODES * 4;       // 0.32 MB
    unsigned* bbump   = (unsigned*)(ws + off); off += (size_t)NBKT * BBSTRIDE * 4; // 20 KB
    double*   partial2= (double*)(ws + off);   off += (size_t)G2_BLOCKS * 8;     // 0.08 MB
    (void)ws_size; (void)in_sizes; (void)n_in; (void)out_size;

    const int B = 256;
    k_initb<<<(NBKT + B - 1) / B, B, 0, stream>>>(bbump);
    k_binfill<<<BF_BLOCKS, BF_THREADS, 0, stream>>>(ei, bbump, stage);
    k_place<<<NBKT, B, 0, stream>>>(bbump, stage, csr, row_ptr, rend, dinv);

    k_gemm1<<<G1_BLOCKS, B, 0, stream>>>(x, W1, dinv, xW1h);
    k_gather1_gemm2<<<N_NODES / 8, B, 0, stream>>>(row_ptr, rend, csr, xW1h, dinv, b1, W2, h2h);
    k_gather2_final<<<G2_BLOCKS, B, 0, stream>>>(row_ptr, rend, csr, h2h, dinv, b2, Wout, partial2);

    k_reduce<<<NB, B, 0, stream>>>(partial2, bout, out);
}

// Round 20
// 174.965 us; speedup vs baseline: 1.1400x; 1.0044x over previous
//
#include <hip/hip_runtime.h>
#include <hip/hip_fp16.h>

// Problem constants (match reference)
constexpr int   N_NODES = 80000;
constexpr int   N_EDGE  = 2560000;
constexpr int   IN_DIM  = 128;
constexpr int   H1      = 32;
constexpr int   H2      = 64;
constexpr int   NPB     = 10000;   // nodes per batch
constexpr int   NB      = 8;       // batches
constexpr int   G2_BLOCKS = N_NODES / 8;        // 10000 (8 nodes per block)
constexpr int   BLK_PER_BATCH = G2_BLOCKS / NB; // 1250

// binned-fill parameters (static bucket capacity, 256 nodes per bucket)
constexpr int   BKT_SHIFT = 8;                       // 256 nodes per bucket
constexpr int   BKT_N     = 1 << BKT_SHIFT;          // 256
constexpr int   NBKT      = (N_NODES + BKT_N - 1) >> BKT_SHIFT;  // 313
constexpr int   BBSTRIDE  = 16;                      // pad bucket counters to 64 B
constexpr unsigned SBKT_CAP = 9216;                  // mean 8192 + ~11 sigma
constexpr int   BF_EPB    = 4096;                    // edges per binfill block
constexpr int   BF_BLOCKS = N_EDGE / BF_EPB;         // 625 (exact)
constexpr int   BF_THREADS = 512;
constexpr int   BF_EPT    = BF_EPB / BF_THREADS;     // 8 edges per thread

// gemm1 tile parameters
constexpr int   G1_ROWS   = 64;                      // rows per block tile
constexpr int   G1_BLOCKS = N_NODES / G1_ROWS;       // 1250

// ---------------- seed bucket bumps with static bases ----------------
__global__ void k_initb(unsigned* __restrict__ bbump) {
    int i = blockIdx.x * blockDim.x + threadIdx.x;
    if (i < NBKT) bbump[i * BBSTRIDE] = (unsigned)i * SBKT_CAP;
}

// ------- binned fill: stage[pos] = (src<<8)|d_local, dense per bucket ------
// EPB 4096 (625 blocks, 2.4/CU) for latency hiding; dst values cached in
// registers during the hist pass so the fill pass reads only src.
__global__ __launch_bounds__(BF_THREADS) void k_binfill(
        const int* __restrict__ ei, unsigned* __restrict__ bbump,
        unsigned* __restrict__ stage) {
    __shared__ unsigned hist[NBKT];
    __shared__ unsigned base[NBKT];
    int t = threadIdx.x;
    int e0 = blockIdx.x * BF_EPB;
    for (int i = t; i < NBKT; i += BF_THREADS) hist[i] = 0u;
    __syncthreads();
    unsigned dcache[BF_EPT];
#pragma unroll
    for (int k = 0; k < BF_EPT; ++k) {
        unsigned d = (unsigned)ei[N_EDGE + e0 + t + k * BF_THREADS];
        dcache[k] = d;
        atomicAdd(&hist[d >> BKT_SHIFT], 1u);
    }
    __syncthreads();
    for (int i = t; i < NBKT; i += BF_THREADS) {
        unsigned h = hist[i];
        base[i] = h ? atomicAdd(&bbump[i * BBSTRIDE], h) : 0u;
        hist[i] = 0u;
    }
    __syncthreads();
#pragma unroll
    for (int k = 0; k < BF_EPT; ++k) {
        int s = ei[e0 + t + k * BF_THREADS];
        unsigned d = dcache[k];
        int bkt = (int)(d >> BKT_SHIFT);
        unsigned lp = atomicAdd(&hist[bkt], 1u);
        unsigned pos = base[bkt] + lp;
        if (pos < (unsigned)(bkt + 1) * SBKT_CAP)   // capacity guard (never hit)
            stage[pos] = ((unsigned)s << BKT_SHIFT) | (d & (BKT_N - 1u));
    }
}

// ------- place: per-bucket degrees (LDS) -> row_ptr, rend, dinv, csr -------
__global__ __launch_bounds__(256) void k_place(
        const unsigned* __restrict__ bbump, const unsigned* __restrict__ stage,
        int* __restrict__ csr, unsigned* __restrict__ row_ptr,
        unsigned* __restrict__ rend, float* __restrict__ dinv) {
    __shared__ unsigned cnt[BKT_N];
    __shared__ unsigned sc[BKT_N];
    __shared__ unsigned nb[BKT_N];
    int b = blockIdx.x;
    int t = threadIdx.x;              // 256 threads == BKT_N
    unsigned beg = (unsigned)b * SBKT_CAP;
    unsigned end = min(bbump[b * BBSTRIDE], (unsigned)(b + 1) * SBKT_CAP);
    cnt[t] = 0u;
    __syncthreads();
    for (unsigned j = beg + (unsigned)t; j < end; j += 256)
        atomicAdd(&cnt[stage[j] & (BKT_N - 1u)], 1u);
    __syncthreads();
    sc[t] = cnt[t];
    for (int ofs = 1; ofs < BKT_N; ofs <<= 1) {
        __syncthreads();
        unsigned u = (t >= ofs) ? sc[t - ofs] : 0u;
        __syncthreads();
        sc[t] += u;
    }
    __syncthreads();
    {
        unsigned nodebase = beg + sc[t] - cnt[t];
        int node = (b << BKT_SHIFT) + t;
        if (node < N_NODES) {
            row_ptr[node] = nodebase;
            rend[node]    = nodebase + cnt[t];
            dinv[node] = rsqrtf((float)(cnt[t] + 1u));   // +1 self loop
        }
        nb[t] = nodebase;
    }
    __syncthreads();
    for (unsigned j = beg + (unsigned)t; j < end; j += 256) {
        unsigned v = stage[j];
        unsigned pos = atomicAdd(&nb[v & (BKT_N - 1u)], 1u);
        csr[pos] = (int)(v >> BKT_SHIFT);
    }
}

// ------- GEMM1 (LDS-staged x-tile, 8-row blocking): xW1h = fp16((x@W1)*dinv)
__global__ __launch_bounds__(256) void k_gemm1(
        const float* __restrict__ x, const float* __restrict__ W1,
        const float* __restrict__ dinv, __half* __restrict__ xW1h) {
    __shared__ float W1s[IN_DIM * H1];      // 16 KB
    __shared__ float xs[G1_ROWS * IN_DIM];  // 32 KB
    int tid = threadIdx.x;
    for (int i = tid; i < IN_DIM * H1; i += 256) W1s[i] = W1[i];
    // coalesced x-tile stage: 2048 float4, 8 per thread
    int row0 = blockIdx.x * G1_ROWS;
    const float4* src4 = reinterpret_cast<const float4*>(x + (size_t)row0 * IN_DIM);
    float4* xs4 = reinterpret_cast<float4*>(xs);
#pragma unroll
    for (int k = 0; k < 8; ++k) xs4[tid + k * 256] = src4[tid + k * 256];
    __syncthreads();
    int c = tid & 31, g = tid >> 5;   // 8 groups x 8 rows
    float acc[8] = {0.f, 0.f, 0.f, 0.f, 0.f, 0.f, 0.f, 0.f};
    for (int j = 0; j < IN_DIM / 4; ++j) {
        float w0 = W1s[(4 * j + 0) * H1 + c];
        float w1 = W1s[(4 * j + 1) * H1 + c];
        float w2 = W1s[(4 * j + 2) * H1 + c];
        float w3 = W1s[(4 * j + 3) * H1 + c];
#pragma unroll
        for (int r = 0; r < 8; ++r) {
            float4 a = *reinterpret_cast<const float4*>(&xs[((g * 8 + r) << 7) + 4 * j]);
            acc[r] += a.x * w0 + a.y * w1 + a.z * w2 + a.w * w3;
        }
    }
#pragma unroll
    for (int r = 0; r < 8; ++r) {
        int row = row0 + g * 8 + r;
        xW1h[(size_t)row * H1 + c] = __float2half(acc[r] * dinv[row]);
    }
}

// ------- gather layer 1 FUSED with GEMM2 — 2 nodes per wave -------
__global__ __launch_bounds__(256) void k_gather1_gemm2(
        const unsigned* __restrict__ row_ptr, const unsigned* __restrict__ rend,
        const int* __restrict__ csr, const __half* __restrict__ xW1h,
        const float* __restrict__ dinv, const float* __restrict__ b1,
        const float* __restrict__ W2, __half* __restrict__ h2h) {
    int wave = threadIdx.x >> 6;
    int lane = threadIdx.x & 63;
    int h = lane >> 5;                  // node half (0/1)
    int q = (lane >> 2) & 7;            // edge slot 0..7
    int t = lane & 3;                   // feature quad: features 8t..8t+7
    int d = blockIdx.x * 8 + wave * 2 + h;
    unsigned beg = row_ptr[d], end = rend[d];
    float acc[8] = {0.f, 0.f, 0.f, 0.f, 0.f, 0.f, 0.f, 0.f};
    const __half2 one2  = __float2half2_rn(1.0f);
    const __half2 zero2 = __float2half2_rn(0.0f);
    for (unsigned base = beg; base < end; base += 32) {
        __half2 hacc[4] = {zero2, zero2, zero2, zero2};
#pragma unroll
        for (int it = 0; it < 2; ++it) {
            unsigned j0 = base + (unsigned)(it * 16) + (unsigned)q;
            unsigned j1 = j0 + 8u;
            int     s0 = (j0 < end) ? csr[j0] : 0;
            __half2 m0 = (j0 < end) ? one2 : zero2;
            int     s1 = (j1 < end) ? csr[j1] : 0;
            __half2 m1 = (j1 < end) ? one2 : zero2;
            float4 raw0 = *reinterpret_cast<const float4*>(xW1h + (size_t)s0 * H1 + 8 * t);
            float4 raw1 = *reinterpret_cast<const float4*>(xW1h + (size_t)s1 * H1 + 8 * t);
            const __half2* h0 = reinterpret_cast<const __half2*>(&raw0);
            const __half2* h1 = reinterpret_cast<const __half2*>(&raw1);
#pragma unroll
            for (int i = 0; i < 4; ++i) {
                hacc[i] = __hfma2(h0[i], m0, hacc[i]);
                hacc[i] = __hfma2(h1[i], m1, hacc[i]);
            }
        }
#pragma unroll
        for (int i = 0; i < 4; ++i) {
            float2 f = __half22float2(hacc[i]);
            acc[2 * i]     += f.x;
            acc[2 * i + 1] += f.y;
        }
    }
    // reduce across the 8 edge slots (stays within each 32-lane half)
#pragma unroll
    for (int m = 4; m <= 16; m <<= 1)
#pragma unroll
        for (int i = 0; i < 8; ++i)
            acc[i] += __shfl_xor(acc[i], m, 64);
    // ---- fused GEMM2 epilogue (all lanes active; 2 cols per lane) ----
    float dv = dinv[d];
    float4 sraw = *reinterpret_cast<const float4*>(xW1h + (size_t)d * H1 + 8 * t);
    const __half2* sh = reinterpret_cast<const __half2*>(&sraw);
    float rel[8];
#pragma unroll
    for (int i = 0; i < 4; ++i) {
        float2 f = __half22float2(sh[i]);
        rel[2 * i]     = fmaxf((acc[2 * i]     + f.x) * dv + b1[8 * t + 2 * i],     0.f);
        rel[2 * i + 1] = fmaxf((acc[2 * i + 1] + f.y) * dv + b1[8 * t + 2 * i + 1], 0.f);
    }
    int c = lane & 31;
    float h2a = 0.f, h2b = 0.f;
#pragma unroll
    for (int k = 0; k < H1; ++k) {
        int src = (lane & 32) | (k >> 3);            // q=0, t=k>>3 in same half
        float r = __shfl(rel[k & 7], src, 64);
        h2a += r * W2[k * H2 + c];                   // coalesced, L1/L2-hot
        h2b += r * W2[k * H2 + c + 32];
    }
    h2h[(size_t)d * H2 + c]      = __float2half(h2a * dv);
    h2h[(size_t)d * H2 + c + 32] = __float2half(h2b * dv);
}

// ------- gather layer 2 FUSED with readout — 2 nodes per wave -------
__global__ __launch_bounds__(256) void k_gather2_final(
        const unsigned* __restrict__ row_ptr, const unsigned* __restrict__ rend,
        const int* __restrict__ csr, const __half* __restrict__ h2h,
        const float* __restrict__ dinv, const float* __restrict__ b2,
        const float* __restrict__ Wout, double* __restrict__ partial2) {
    int wave = threadIdx.x >> 6;
    int lane = threadIdx.x & 63;
    int h = lane >> 5;                 // node half (0/1)
    int o = (lane >> 3) & 3;           // edge slot 0..3
    int t = lane & 7;                  // feature octet: features 8t..8t+7
    int d = blockIdx.x * 8 + wave * 2 + h;
    unsigned beg = row_ptr[d], end = rend[d];
    float acc[8] = {0.f, 0.f, 0.f, 0.f, 0.f, 0.f, 0.f, 0.f};
    const __half2 one2  = __float2half2_rn(1.0f);
    const __half2 zero2 = __float2half2_rn(0.0f);
    for (unsigned base = beg; base < end; base += 16) {
        __half2 hacc[4] = {zero2, zero2, zero2, zero2};
#pragma unroll
        for (int it = 0; it < 2; ++it) {
            unsigned j0 = base + (unsigned)(it * 8) + (unsigned)o;
            unsigned j1 = j0 + 4u;
            int     s0 = (j0 < end) ? csr[j0] : 0;
            __half2 m0 = (j0 < end) ? one2 : zero2;
            int     s1 = (j1 < end) ? csr[j1] : 0;
            __half2 m1 = (j1 < end) ? one2 : zero2;
            float4 raw0 = *reinterpret_cast<const float4*>(h2h + (size_t)s0 * H2 + 8 * t);
            float4 raw1 = *reinterpret_cast<const float4*>(h2h + (size_t)s1 * H2 + 8 * t);
            const __half2* h0 = reinterpret_cast<const __half2*>(&raw0);
            const __half2* h1 = reinterpret_cast<const __half2*>(&raw1);
#pragma unroll
            for (int i = 0; i < 4; ++i) {
                hacc[i] = __hfma2(h0[i], m0, hacc[i]);
                hacc[i] = __hfma2(h1[i], m1, hacc[i]);
            }
        }
#pragma unroll
        for (int i = 0; i < 4; ++i) {
            float2 f = __half22float2(hacc[i]);
            acc[2 * i]     += f.x;
            acc[2 * i + 1] += f.y;
        }
    }
    // reduce across the 4 edge slots (stays within each 32-lane half)
#pragma unroll
    for (int m = 8; m <= 16; m <<= 1)
#pragma unroll
        for (int i = 0; i < 8; ++i)
            acc[i] += __shfl_xor(acc[i], m, 64);
    // epilogue: each half's lanes t=0..7 cover 64 features (dup across o)
    float dv = dinv[d];
    float4 sraw = *reinterpret_cast<const float4*>(h2h + (size_t)d * H2 + 8 * t);
    const __half2* sh = reinterpret_cast<const __half2*>(&sraw);
    float4 bb0 = *reinterpret_cast<const float4*>(b2 + 8 * t);
    float4 bb1 = *reinterpret_cast<const float4*>(b2 + 8 * t + 4);
    const float* wrow = Wout + (size_t)(d % NPB) * H2 + 8 * t;
    float4 ww0 = *reinterpret_cast<const float4*>(wrow);
    float4 ww1 = *reinterpret_cast<const float4*>(wrow + 4);
    float self[8];
#pragma unroll
    for (int i = 0; i < 4; ++i) {
        float2 f = __half22float2(sh[i]);
        self[2 * i] = f.x; self[2 * i + 1] = f.y;
    }
    float bbv[8] = {bb0.x, bb0.y, bb0.z, bb0.w, bb1.x, bb1.y, bb1.z, bb1.w};
    float wwv[8] = {ww0.x, ww0.y, ww0.z, ww0.w, ww1.x, ww1.y, ww1.z, ww1.w};
    float fsum = 0.f;
#pragma unroll
    for (int i = 0; i < 8; ++i)
        fsum += fmaxf((acc[i] + self[i]) * dv + bbv[i], 0.f) * wwv[i];
    double dval = (double)fsum;
    // reduce over t = 0..7 (within o-group; dval duplicated across o)
    dval += __shfl_down(dval, 4, 64);
    dval += __shfl_down(dval, 2, 64);
    dval += __shfl_down(dval, 1, 64);
    __shared__ double sdbl[8];
    if ((lane & 31) == 0) sdbl[wave * 2 + h] = dval;
    __syncthreads();
    if (threadIdx.x == 0)
        partial2[blockIdx.x] = ((sdbl[0] + sdbl[1]) + (sdbl[2] + sdbl[3]))
                             + ((sdbl[4] + sdbl[5]) + (sdbl[6] + sdbl[7]));
}

// ------- final reduce: out[b] = sum of partial2[b*1250 .. ) + bout -------
__global__ __launch_bounds__(256) void k_reduce(
        const double* __restrict__ partial2, const float* __restrict__ bout,
        float* __restrict__ out) {
    int b = blockIdx.x;
    int tid = threadIdx.x;
    double acc = 0.0;
    for (int i = tid; i < BLK_PER_BATCH; i += 256)
        acc += partial2[b * BLK_PER_BATCH + i];
    for (int off = 32; off; off >>= 1) acc += __shfl_down(acc, off, 64);
    __shared__ double sred[4];
    if ((tid & 63) == 0) sred[tid >> 6] = acc;
    __syncthreads();
    if (tid == 0)
        out[b] = (float)(((sred[0] + sred[1]) + (sred[2] + sred[3])) + (double)bout[0]);
}

extern "C" void kernel_launch(void* const* d_in, const int* in_sizes, int n_in,
                              void* d_out, int out_size, void* d_ws, size_t ws_size,
                              hipStream_t stream) {
    const float* x    = (const float*)d_in[0];
    const int*   ei   = (const int*)d_in[1];    // int32 (JAX x64 disabled)
    const float* W1   = (const float*)d_in[2];
    const float* b1   = (const float*)d_in[3];
    const float* W2   = (const float*)d_in[4];
    const float* b2   = (const float*)d_in[5];
    const float* Wout = (const float*)d_in[6];
    const float* bout = (const float*)d_in[7];
    float* out = (float*)d_out;

    // workspace layout — no aliasing, total ~40 MB
    constexpr size_t STATIC_SZ = (size_t)NBKT * SBKT_CAP;   // 2.885M entries
    char* ws = (char*)d_ws;
    size_t off = 0;
    int*      csr     = (int*)(ws + off);      off += STATIC_SZ * 4;             // 11.54 MB
    unsigned* stage   = (unsigned*)(ws + off); off += STATIC_SZ * 4;             // 11.54 MB
    __half*   xW1h    = (__half*)(ws + off);   off += (size_t)N_NODES * H1 * 2;  // 5.12 MB
    __half*   h2h     = (__half*)(ws + off);   off += (size_t)N_NODES * H2 * 2;  // 10.24 MB
    unsigned* row_ptr = (unsigned*)(ws + off); off += (size_t)N_NODES * 4;       // 0.32 MB
    unsigned* rend    = (unsigned*)(ws + off); off += (size_t)N_NODES * 4;       // 0.32 MB
    float*    dinv    = (float*)(ws + off);    off += (size_t)N_NODES * 4;       // 0.32 MB
    unsigned* bbump   = (unsigned*)(ws + off); off += (size_t)NBKT * BBSTRIDE * 4; // 20 KB
    double*   partial2= (double*)(ws + off);   off += (size_t)G2_BLOCKS * 8;     // 0.08 MB
    (void)ws_size; (void)in_sizes; (void)n_in; (void)out_size;

    const int B = 256;
    k_initb<<<(NBKT + B - 1) / B, B, 0, stream>>>(bbump);
    k_binfill<<<BF_BLOCKS, BF_THREADS, 0, stream>>>(ei, bbump, stage);
    k_place<<<NBKT, B, 0, stream>>>(bbump, stage, csr, row_ptr, rend, dinv);

    k_gemm1<<<G1_BLOCKS, B, 0, stream>>>(x, W1, dinv, xW1h);
    k_gather1_gemm2<<<N_NODES / 8, B, 0, stream>>>(row_ptr, rend, csr, xW1h, dinv, b1, W2, h2h);
    k_gather2_final<<<G2_BLOCKS, B, 0, stream>>>(row_ptr, rend, csr, h2h, dinv, b2, Wout, partial2);

    k_reduce<<<NB, B, 0, stream>>>(partial2, bout, out);
}

// Round 21
// 169.512 us; speedup vs baseline: 1.1766x; 1.0322x over previous
//
#include <hip/hip_runtime.h>
#include <hip/hip_fp16.h>

// Problem constants (match reference)
constexpr int   N_NODES = 80000;
constexpr int   N_EDGE  = 2560000;
constexpr int   IN_DIM  = 128;
constexpr int   H1      = 32;
constexpr int   H2      = 64;
constexpr int   NPB     = 10000;   // nodes per batch
constexpr int   NB      = 8;       // batches
constexpr int   G2_BLOCKS = N_NODES / 8;        // 10000 (8 nodes per block)
constexpr int   BLK_PER_BATCH = G2_BLOCKS / NB; // 1250

// binned-fill parameters (static bucket capacity, 256 nodes per bucket)
constexpr int   BKT_SHIFT = 8;                       // 256 nodes per bucket
constexpr int   BKT_N     = 1 << BKT_SHIFT;          // 256
constexpr int   NBKT      = (N_NODES + BKT_N - 1) >> BKT_SHIFT;  // 313
constexpr int   BBSTRIDE  = 16;                      // pad bucket counters to 64 B
constexpr unsigned SBKT_CAP = 9216;                  // mean 8192 + ~11 sigma
constexpr int   BF_EPB    = 4096;                    // edges per binfill block
constexpr int   BF_BLOCKS = N_EDGE / BF_EPB;         // 625 (exact)
constexpr int   FB_THREADS = 512;                    // fused kernel block size
constexpr int   BF_EPT    = BF_EPB / FB_THREADS;     // 8 edges per thread

// gemm1 tile parameters (fused branch)
constexpr int   G1_ROWS   = 64;                      // rows per block tile
constexpr int   G1_BLOCKS = N_NODES / G1_ROWS;       // 1250
constexpr int   FUSED_BLOCKS = BF_BLOCKS + G1_BLOCKS; // 1875

// ---------------- seed bucket bumps with static bases ----------------
__global__ void k_initb(unsigned* __restrict__ bbump) {
    int i = blockIdx.x * blockDim.x + threadIdx.x;
    if (i < NBKT) bbump[i * BBSTRIDE] = (unsigned)i * SBKT_CAP;
}

// ------- FUSED: binfill (blocks < BF_BLOCKS) + gemm1-raw (rest) -------
// binfill: stage[pos] = (src<<8)|d_local, dense per bucket; dst cached in
// registers. gemm1: xW1h = fp16(x @ W1) UNSCALED (dinv applied in k_place).
// The latency-bound binfill waves overlap with gemm1's FMA-heavy waves.
__global__ __launch_bounds__(FB_THREADS) void k_binfill_gemm1(
        const int* __restrict__ ei, unsigned* __restrict__ bbump,
        unsigned* __restrict__ stage,
        const float* __restrict__ x, const float* __restrict__ W1,
        __half* __restrict__ xW1h) {
    __shared__ __align__(16) char smem[49152];   // union: 48 KB
    int t = threadIdx.x;
    if (blockIdx.x < BF_BLOCKS) {
        // ---------------- binfill branch ----------------
        unsigned* hist = (unsigned*)smem;            // NBKT
        unsigned* base = hist + NBKT;                // NBKT
        int e0 = blockIdx.x * BF_EPB;
        for (int i = t; i < NBKT; i += FB_THREADS) hist[i] = 0u;
        __syncthreads();
        unsigned dcache[BF_EPT];
#pragma unroll
        for (int k = 0; k < BF_EPT; ++k) {
            unsigned d = (unsigned)ei[N_EDGE + e0 + t + k * FB_THREADS];
            dcache[k] = d;
            atomicAdd(&hist[d >> BKT_SHIFT], 1u);
        }
        __syncthreads();
        for (int i = t; i < NBKT; i += FB_THREADS) {
            unsigned h = hist[i];
            base[i] = h ? atomicAdd(&bbump[i * BBSTRIDE], h) : 0u;
            hist[i] = 0u;
        }
        __syncthreads();
#pragma unroll
        for (int k = 0; k < BF_EPT; ++k) {
            int s = ei[e0 + t + k * FB_THREADS];
            unsigned d = dcache[k];
            int bkt = (int)(d >> BKT_SHIFT);
            unsigned lp = atomicAdd(&hist[bkt], 1u);
            unsigned pos = base[bkt] + lp;
            if (pos < (unsigned)(bkt + 1) * SBKT_CAP)   // guard (never hit)
                stage[pos] = ((unsigned)s << BKT_SHIFT) | (d & (BKT_N - 1u));
        }
    } else {
        // ---------------- gemm1 branch (unscaled) ----------------
        float* W1s = (float*)smem;                   // 16 KB
        float* xs  = W1s + IN_DIM * H1;              // 32 KB
        int bb = blockIdx.x - BF_BLOCKS;
        int row0 = bb * G1_ROWS;
        for (int i = t; i < IN_DIM * H1; i += FB_THREADS) W1s[i] = W1[i];
        const float4* src4 = reinterpret_cast<const float4*>(x + (size_t)row0 * IN_DIM);
        float4* xs4 = reinterpret_cast<float4*>(xs);
#pragma unroll
        for (int k = 0; k < 4; ++k) xs4[t + k * FB_THREADS] = src4[t + k * FB_THREADS];
        __syncthreads();
        int c = t & 31, g = t >> 5;                  // 16 groups x 4 rows
        float acc[4] = {0.f, 0.f, 0.f, 0.f};
        for (int j = 0; j < IN_DIM / 4; ++j) {
            float w0 = W1s[(4 * j + 0) * H1 + c];
            float w1 = W1s[(4 * j + 1) * H1 + c];
            float w2 = W1s[(4 * j + 2) * H1 + c];
            float w3 = W1s[(4 * j + 3) * H1 + c];
#pragma unroll
            for (int r = 0; r < 4; ++r) {
                float4 a = *reinterpret_cast<const float4*>(&xs[((g * 4 + r) << 7) + 4 * j]);
                acc[r] += a.x * w0 + a.y * w1 + a.z * w2 + a.w * w3;
            }
        }
#pragma unroll
        for (int r = 0; r < 4; ++r) {
            int row = row0 + g * 4 + r;
            xW1h[(size_t)row * H1 + c] = __float2half(acc[r]);   // unscaled
        }
    }
}

// ------- place: per-bucket degrees -> row_ptr, rend, dinv, csr; then ------
// scale this bucket's xW1h rows by dinv (moved out of gemm1 for the fusion).
__global__ __launch_bounds__(256) void k_place(
        const unsigned* __restrict__ bbump, const unsigned* __restrict__ stage,
        int* __restrict__ csr, unsigned* __restrict__ row_ptr,
        unsigned* __restrict__ rend, float* __restrict__ dinv,
        __half* __restrict__ xW1h) {
    __shared__ unsigned cnt[BKT_N];
    __shared__ unsigned sc[BKT_N];
    __shared__ unsigned nb[BKT_N];
    __shared__ float    dvs[BKT_N];
    int b = blockIdx.x;
    int t = threadIdx.x;              // 256 threads == BKT_N
    unsigned beg = (unsigned)b * SBKT_CAP;
    unsigned end = min(bbump[b * BBSTRIDE], (unsigned)(b + 1) * SBKT_CAP);
    cnt[t] = 0u;
    __syncthreads();
    for (unsigned j = beg + (unsigned)t; j < end; j += 256)
        atomicAdd(&cnt[stage[j] & (BKT_N - 1u)], 1u);
    __syncthreads();
    sc[t] = cnt[t];
    for (int ofs = 1; ofs < BKT_N; ofs <<= 1) {
        __syncthreads();
        unsigned u = (t >= ofs) ? sc[t - ofs] : 0u;
        __syncthreads();
        sc[t] += u;
    }
    __syncthreads();
    {
        float dvloc = rsqrtf((float)(cnt[t] + 1u));   // +1 self loop
        unsigned nodebase = beg + sc[t] - cnt[t];
        int node = (b << BKT_SHIFT) + t;
        if (node < N_NODES) {
            row_ptr[node] = nodebase;
            rend[node]    = nodebase + cnt[t];
            dinv[node] = dvloc;
        }
        nb[t] = nodebase;
        dvs[t] = dvloc;
    }
    __syncthreads();
    for (unsigned j = beg + (unsigned)t; j < end; j += 256) {
        unsigned v = stage[j];
        unsigned pos = atomicAdd(&nb[v & (BKT_N - 1u)], 1u);
        csr[pos] = (int)(v >> BKT_SHIFT);
    }
    // ---- scale epilogue: xW1h rows of this bucket *= dinv (coalesced) ----
    int n0 = b << BKT_SHIFT;
    int nvalid = min(BKT_N, N_NODES - n0);
    __half2* rows = reinterpret_cast<__half2*>(xW1h + (size_t)n0 * H1);
    for (int idx = t; idx < nvalid * (H1 / 2); idx += 256) {
        float dv = dvs[idx >> 4];                    // 16 half2 per row
        float2 f = __half22float2(rows[idx]);
        rows[idx] = __floats2half2_rn(f.x * dv, f.y * dv);
    }
}

// ------- gather layer 1 FUSED with GEMM2 — 2 nodes per wave -------
__global__ __launch_bounds__(256) void k_gather1_gemm2(
        const unsigned* __restrict__ row_ptr, const unsigned* __restrict__ rend,
        const int* __restrict__ csr, const __half* __restrict__ xW1h,
        const float* __restrict__ dinv, const float* __restrict__ b1,
        const float* __restrict__ W2, __half* __restrict__ h2h) {
    int wave = threadIdx.x >> 6;
    int lane = threadIdx.x & 63;
    int h = lane >> 5;                  // node half (0/1)
    int q = (lane >> 2) & 7;            // edge slot 0..7
    int t = lane & 3;                   // feature quad: features 8t..8t+7
    int d = blockIdx.x * 8 + wave * 2 + h;
    unsigned beg = row_ptr[d], end = rend[d];
    float acc[8] = {0.f, 0.f, 0.f, 0.f, 0.f, 0.f, 0.f, 0.f};
    const __half2 one2  = __float2half2_rn(1.0f);
    const __half2 zero2 = __float2half2_rn(0.0f);
    for (unsigned base = beg; base < end; base += 32) {
        __half2 hacc[4] = {zero2, zero2, zero2, zero2};
#pragma unroll
        for (int it = 0; it < 2; ++it) {
            unsigned j0 = base + (unsigned)(it * 16) + (unsigned)q;
            unsigned j1 = j0 + 8u;
            int     s0 = (j0 < end) ? csr[j0] : 0;
            __half2 m0 = (j0 < end) ? one2 : zero2;
            int     s1 = (j1 < end) ? csr[j1] : 0;
            __half2 m1 = (j1 < end) ? one2 : zero2;
            float4 raw0 = *reinterpret_cast<const float4*>(xW1h + (size_t)s0 * H1 + 8 * t);
            float4 raw1 = *reinterpret_cast<const float4*>(xW1h + (size_t)s1 * H1 + 8 * t);
            const __half2* h0 = reinterpret_cast<const __half2*>(&raw0);
            const __half2* h1 = reinterpret_cast<const __half2*>(&raw1);
#pragma unroll
            for (int i = 0; i < 4; ++i) {
                hacc[i] = __hfma2(h0[i], m0, hacc[i]);
                hacc[i] = __hfma2(h1[i], m1, hacc[i]);
            }
        }
#pragma unroll
        for (int i = 0; i < 4; ++i) {
            float2 f = __half22float2(hacc[i]);
            acc[2 * i]     += f.x;
            acc[2 * i + 1] += f.y;
        }
    }
    // reduce across the 8 edge slots (stays within each 32-lane half)
#pragma unroll
    for (int m = 4; m <= 16; m <<= 1)
#pragma unroll
        for (int i = 0; i < 8; ++i)
            acc[i] += __shfl_xor(acc[i], m, 64);
    // ---- fused GEMM2 epilogue (all lanes active; 2 cols per lane) ----
    float dv = dinv[d];
    float4 sraw = *reinterpret_cast<const float4*>(xW1h + (size_t)d * H1 + 8 * t);
    const __half2* sh = reinterpret_cast<const __half2*>(&sraw);
    float rel[8];
#pragma unroll
    for (int i = 0; i < 4; ++i) {
        float2 f = __half22float2(sh[i]);
        rel[2 * i]     = fmaxf((acc[2 * i]     + f.x) * dv + b1[8 * t + 2 * i],     0.f);
        rel[2 * i + 1] = fmaxf((acc[2 * i + 1] + f.y) * dv + b1[8 * t + 2 * i + 1], 0.f);
    }
    int c = lane & 31;
    float h2a = 0.f, h2b = 0.f;
#pragma unroll
    for (int k = 0; k < H1; ++k) {
        int src = (lane & 32) | (k >> 3);            // q=0, t=k>>3 in same half
        float r = __shfl(rel[k & 7], src, 64);
        h2a += r * W2[k * H2 + c];                   // coalesced, L1/L2-hot
        h2b += r * W2[k * H2 + c + 32];
    }
    h2h[(size_t)d * H2 + c]      = __float2half(h2a * dv);
    h2h[(size_t)d * H2 + c + 32] = __float2half(h2b * dv);
}

// ------- gather layer 2 FUSED with readout — 2 nodes per wave -------
__global__ __launch_bounds__(256) void k_gather2_final(
        const unsigned* __restrict__ row_ptr, const unsigned* __restrict__ rend,
        const int* __restrict__ csr, const __half* __restrict__ h2h,
        const float* __restrict__ dinv, const float* __restrict__ b2,
        const float* __restrict__ Wout, double* __restrict__ partial2) {
    int wave = threadIdx.x >> 6;
    int lane = threadIdx.x & 63;
    int h = lane >> 5;                 // node half (0/1)
    int o = (lane >> 3) & 3;           // edge slot 0..3
    int t = lane & 7;                  // feature octet: features 8t..8t+7
    int d = blockIdx.x * 8 + wave * 2 + h;
    unsigned beg = row_ptr[d], end = rend[d];
    float acc[8] = {0.f, 0.f, 0.f, 0.f, 0.f, 0.f, 0.f, 0.f};
    const __half2 one2  = __float2half2_rn(1.0f);
    const __half2 zero2 = __float2half2_rn(0.0f);
    for (unsigned base = beg; base < end; base += 16) {
        __half2 hacc[4] = {zero2, zero2, zero2, zero2};
#pragma unroll
        for (int it = 0; it < 2; ++it) {
            unsigned j0 = base + (unsigned)(it * 8) + (unsigned)o;
            unsigned j1 = j0 + 4u;
            int     s0 = (j0 < end) ? csr[j0] : 0;
            __half2 m0 = (j0 < end) ? one2 : zero2;
            int     s1 = (j1 < end) ? csr[j1] : 0;
            __half2 m1 = (j1 < end) ? one2 : zero2;
            float4 raw0 = *reinterpret_cast<const float4*>(h2h + (size_t)s0 * H2 + 8 * t);
            float4 raw1 = *reinterpret_cast<const float4*>(h2h + (size_t)s1 * H2 + 8 * t);
            const __half2* h0 = reinterpret_cast<const __half2*>(&raw0);
            const __half2* h1 = reinterpret_cast<const __half2*>(&raw1);
#pragma unroll
            for (int i = 0; i < 4; ++i) {
                hacc[i] = __hfma2(h0[i], m0, hacc[i]);
                hacc[i] = __hfma2(h1[i], m1, hacc[i]);
            }
        }
#pragma unroll
        for (int i = 0; i < 4; ++i) {
            float2 f = __half22float2(hacc[i]);
            acc[2 * i]     += f.x;
            acc[2 * i + 1] += f.y;
        }
    }
    // reduce across the 4 edge slots (stays within each 32-lane half)
#pragma unroll
    for (int m = 8; m <= 16; m <<= 1)
#pragma unroll
        for (int i = 0; i < 8; ++i)
            acc[i] += __shfl_xor(acc[i], m, 64);
    // epilogue: each half's lanes t=0..7 cover 64 features (dup across o)
    float dv = dinv[d];
    float4 sraw = *reinterpret_cast<const float4*>(h2h + (size_t)d * H2 + 8 * t);
    const __half2* sh = reinterpret_cast<const __half2*>(&sraw);
    float4 bb0 = *reinterpret_cast<const float4*>(b2 + 8 * t);
    float4 bb1 = *reinterpret_cast<const float4*>(b2 + 8 * t + 4);
    const float* wrow = Wout + (size_t)(d % NPB) * H2 + 8 * t;
    float4 ww0 = *reinterpret_cast<const float4*>(wrow);
    float4 ww1 = *reinterpret_cast<const float4*>(wrow + 4);
    float self[8];
#pragma unroll
    for (int i = 0; i < 4; ++i) {
        float2 f = __half22float2(sh[i]);
        self[2 * i] = f.x; self[2 * i + 1] = f.y;
    }
    float bbv[8] = {bb0.x, bb0.y, bb0.z, bb0.w, bb1.x, bb1.y, bb1.z, bb1.w};
    float wwv[8] = {ww0.x, ww0.y, ww0.z, ww0.w, ww1.x, ww1.y, ww1.z, ww1.w};
    float fsum = 0.f;
#pragma unroll
    for (int i = 0; i < 8; ++i)
        fsum += fmaxf((acc[i] + self[i]) * dv + bbv[i], 0.f) * wwv[i];
    double dval = (double)fsum;
    // reduce over t = 0..7 (within o-group; dval duplicated across o)
    dval += __shfl_down(dval, 4, 64);
    dval += __shfl_down(dval, 2, 64);
    dval += __shfl_down(dval, 1, 64);
    __shared__ double sdbl[8];
    if ((lane & 31) == 0) sdbl[wave * 2 + h] = dval;
    __syncthreads();
    if (threadIdx.x == 0)
        partial2[blockIdx.x] = ((sdbl[0] + sdbl[1]) + (sdbl[2] + sdbl[3]))
                             + ((sdbl[4] + sdbl[5]) + (sdbl[6] + sdbl[7]));
}

// ------- final reduce: out[b] = sum of partial2[b*1250 .. ) + bout -------
__global__ __launch_bounds__(256) void k_reduce(
        const double* __restrict__ partial2, const float* __restrict__ bout,
        float* __restrict__ out) {
    int b = blockIdx.x;
    int tid = threadIdx.x;
    double acc = 0.0;
    for (int i = tid; i < BLK_PER_BATCH; i += 256)
        acc += partial2[b * BLK_PER_BATCH + i];
    for (int off = 32; off; off >>= 1) acc += __shfl_down(acc, off, 64);
    __shared__ double sred[4];
    if ((tid & 63) == 0) sred[tid >> 6] = acc;
    __syncthreads();
    if (tid == 0)
        out[b] = (float)(((sred[0] + sred[1]) + (sred[2] + sred[3])) + (double)bout[0]);
}

extern "C" void kernel_launch(void* const* d_in, const int* in_sizes, int n_in,
                              void* d_out, int out_size, void* d_ws, size_t ws_size,
                              hipStream_t stream) {
    const float* x    = (const float*)d_in[0];
    const int*   ei   = (const int*)d_in[1];    // int32 (JAX x64 disabled)
    const float* W1   = (const float*)d_in[2];
    const float* b1   = (const float*)d_in[3];
    const float* W2   = (const float*)d_in[4];
    const float* b2   = (const float*)d_in[5];
    const float* Wout = (const float*)d_in[6];
    const float* bout = (const float*)d_in[7];
    float* out = (float*)d_out;

    // workspace layout — no aliasing, total ~40 MB
    constexpr size_t STATIC_SZ = (size_t)NBKT * SBKT_CAP;   // 2.885M entries
    char* ws = (char*)d_ws;
    size_t off = 0;
    int*      csr     = (int*)(ws + off);      off += STATIC_SZ * 4;             // 11.54 MB
    unsigned* stage   = (unsigned*)(ws + off); off += STATIC_SZ * 4;             // 11.54 MB
    __half*   xW1h    = (__half*)(ws + off);   off += (size_t)N_NODES * H1 * 2;  // 5.12 MB
    __half*   h2h     = (__half*)(ws + off);   off += (size_t)N_NODES * H2 * 2;  // 10.24 MB
    unsigned* row_ptr = (unsigned*)(ws + off); off += (size_t)N_NODES * 4;       // 0.32 MB
    unsigned* rend    = (unsigned*)(ws + off); off += (size_t)N_NODES * 4;       // 0.32 MB
    float*    dinv    = (float*)(ws + off);    off += (size_t)N_NODES * 4;       // 0.32 MB
    unsigned* bbump   = (unsigned*)(ws + off); off += (size_t)NBKT * BBSTRIDE * 4; // 20 KB
    double*   partial2= (double*)(ws + off);   off += (size_t)G2_BLOCKS * 8;     // 0.08 MB
    (void)ws_size; (void)in_sizes; (void)n_in; (void)out_size;

    const int B = 256;
    k_initb<<<(NBKT + B - 1) / B, B, 0, stream>>>(bbump);
    k_binfill_gemm1<<<FUSED_BLOCKS, FB_THREADS, 0, stream>>>(ei, bbump, stage, x, W1, xW1h);
    k_place<<<NBKT, B, 0, stream>>>(bbump, stage, csr, row_ptr, rend, dinv, xW1h);

    k_gather1_gemm2<<<N_NODES / 8, B, 0, stream>>>(row_ptr, rend, csr, xW1h, dinv, b1, W2, h2h);
    k_gather2_final<<<G2_BLOCKS, B, 0, stream>>>(row_ptr, rend, csr, h2h, dinv, b2, Wout, partial2);

    k_reduce<<<NB, B, 0, stream>>>(partial2, bout, out);
}